// Round 2
// baseline (2673.206 us; speedup 1.0000x reference)
//
#include <hip/hip_runtime.h>
#include <hip/hip_bf16.h>

// GlobalGuideLayer: B=16, N=8192, C=256, h=4, d=64, N1=64, proj=skip_proj=64.
// Dtypes (established rounds 0-4): ALL fp32, inputs AND output, exactly per
// the reference. fp32 logits are precision-critical (logit std ~50, softmax
// near-one-hot: bf16 kp would shift weights ~20%). No fp32 MFMA on CDNA4 ->
// VALU FMA is the compute floor (kp: 27 us, attn: ~55 us).
#define B_SZ  16
#define N_TOK 8192
#define C_DIM 256
#define NH    4

// ---------------------------------------------------------------------------
// Zero kp region of ws: 262144 floats = 1 MB (vp is fully overwritten by
// vp_kernel's plain stores - no zeroing needed). grid 256 x 256.
// ---------------------------------------------------------------------------
__global__ __launch_bounds__(256) void zero_kernel(float4* __restrict__ p) {
    p[(size_t)blockIdx.x * 256 + threadIdx.x] = make_float4(0.f, 0.f, 0.f, 0.f);
}

// ---------------------------------------------------------------------------
// kp[b,c,k] = sum_n skip[b,n,c]*EF2[n,k], split-K over 32 chunks of 256
// tokens, atomicAdd partials (fp32 order-noise ~1e-6 << tol).
//
// v3 (this round): latency-bound fix. Round-1 counters: VGPR=36 -> compiler
// serialized the "8 loads in flight" through 2-3 registers; VALUBusy 14%,
// 300 us vs 27 us VALU floor. Now: thread (cg=tid&63, kq=tid>>6) owns
// 4 consecutive c (float4 skip loads, 1KB/wave-instr) x 16 k -> acc[64];
// explicit double-buffered prefetch (cur/nxt float4) keeps 8 float4 loads
// live across the 256-FMA body; EF2 chunk (64KB) staged once, 1 barrier.
// __launch_bounds__(256,2): 2 blocks/CU (LDS-capped anyway), VGPR budget
// ~115 so the pipeline isn't register-starved.
// Atomics: 512 blk x 256 thr x 64 = 8.4M lane-ops -> ~262 MB HBM write
// (each device-scope fp32 atomic write-throughs a 32B sector; measured
// round-1: WRITE_SIZE == atomics x 32B exactly).
// grid (32, 16), block 256.
// ---------------------------------------------------------------------------
__global__ __launch_bounds__(256, 2) void kp_atomic_kernel(
    const float* __restrict__ skip,
    const float* __restrict__ ef2,
    float* __restrict__ kp)
{
    __shared__ float ef2_lds[256][64];     // 64 KB: whole 256-token EF2 slab
    const int b = blockIdx.y, s = blockIdx.x;
    const int tid = threadIdx.x;
    const int cg = tid & 63;               // c-group: channels cg*4..cg*4+3
    const int kq = tid >> 6;               // k-quarter: k in [kq*16, kq*16+16)
    const int n0 = s * 256;

    // stage EF2[n0:n0+256, :] -> LDS (4096 float4, 16 per thread)
    {
        const float4* src = reinterpret_cast<const float4*>(ef2 + (size_t)n0 * 64);
        float4* dst_l = reinterpret_cast<float4*>(&ef2_lds[0][0]);
#pragma unroll
        for (int i = 0; i < 16; ++i)
            dst_l[i * 256 + tid] = src[i * 256 + tid];
    }
    __syncthreads();

    float acc[64];
#pragma unroll
    for (int k = 0; k < 64; ++k) acc[k] = 0.f;

    // skip[b, n0+t, cg*4..cg*4+3] as float4: lane-consecutive -> 1KB/instr
    const float4* sp4 = reinterpret_cast<const float4*>(
        skip + ((size_t)b * N_TOK + n0) * C_DIM);

    auto fma4 = [&](int t, float4 v0, float4 v1, float4 v2, float4 v3) {
        float4 vv[4] = {v0, v1, v2, v3};
#pragma unroll
        for (int j = 0; j < 4; ++j) {
            const float4* row = reinterpret_cast<const float4*>(&ef2_lds[t + j][kq * 16]);
            float c0 = vv[j].x, c1 = vv[j].y, c2 = vv[j].z, c3 = vv[j].w;
#pragma unroll
            for (int k4 = 0; k4 < 4; ++k4) {       // LDS broadcast (wave-uniform addr)
                float4 e = row[k4];
                acc[0*16 + k4*4+0] += c0 * e.x;
                acc[0*16 + k4*4+1] += c0 * e.y;
                acc[0*16 + k4*4+2] += c0 * e.z;
                acc[0*16 + k4*4+3] += c0 * e.w;
                acc[1*16 + k4*4+0] += c1 * e.x;
                acc[1*16 + k4*4+1] += c1 * e.y;
                acc[1*16 + k4*4+2] += c1 * e.z;
                acc[1*16 + k4*4+3] += c1 * e.w;
                acc[2*16 + k4*4+0] += c2 * e.x;
                acc[2*16 + k4*4+1] += c2 * e.y;
                acc[2*16 + k4*4+2] += c2 * e.z;
                acc[2*16 + k4*4+3] += c2 * e.w;
                acc[3*16 + k4*4+0] += c3 * e.x;
                acc[3*16 + k4*4+1] += c3 * e.y;
                acc[3*16 + k4*4+2] += c3 * e.z;
                acc[3*16 + k4*4+3] += c3 * e.w;
            }
        }
    };

    float4 cur0 = sp4[0 * 64 + cg];
    float4 cur1 = sp4[1 * 64 + cg];
    float4 cur2 = sp4[2 * 64 + cg];
    float4 cur3 = sp4[3 * 64 + cg];
    for (int t = 0; t < 252; t += 4) {
        // prefetch next 4 tokens while current 4 compute (256 FMA ~ 512 cyc)
        float4 nx0 = sp4[(t + 4) * 64 + cg];
        float4 nx1 = sp4[(t + 5) * 64 + cg];
        float4 nx2 = sp4[(t + 6) * 64 + cg];
        float4 nx3 = sp4[(t + 7) * 64 + cg];
        fma4(t, cur0, cur1, cur2, cur3);
        cur0 = nx0; cur1 = nx1; cur2 = nx2; cur3 = nx3;
    }
    fma4(252, cur0, cur1, cur2, cur3);

#pragma unroll
    for (int ci = 0; ci < 4; ++ci) {
        float* dst = kp + ((size_t)b * C_DIM + cg * 4 + ci) * 64 + kq * 16;
#pragma unroll
        for (int j = 0; j < 16; ++j) atomicAdd(dst + j, acc[ci * 16 + j]);
    }
}

// ---------------------------------------------------------------------------
// vp[b,c,m] = sum_{n1<64} gf[b,n1,c]*EF1[n1,m]. grid 16, block 256.
// ---------------------------------------------------------------------------
__global__ __launch_bounds__(256) void vp_kernel(
    const float* __restrict__ gf,
    const float* __restrict__ ef1,
    float* __restrict__ vp)
{
    __shared__ float ef1_lds[64][64];      // 16 KB
    const int b = blockIdx.x, tid = threadIdx.x;
    const float4* src = reinterpret_cast<const float4*>(ef1);
    float4* dst_l = reinterpret_cast<float4*>(&ef1_lds[0][0]);
#pragma unroll
    for (int i = 0; i < 4; ++i)            // 1024 float4 = 64 x 64
        dst_l[i * 256 + tid] = src[i * 256 + tid];
    __syncthreads();
    float acc[64];
#pragma unroll
    for (int k = 0; k < 64; ++k) acc[k] = 0.f;
    const float* gp = gf + (size_t)b * 64 * C_DIM + tid;
    for (int n = 0; n < 64; ++n) {
        float v = gp[(size_t)n * C_DIM];
        const float4* row = reinterpret_cast<const float4*>(ef1_lds[n]);
#pragma unroll
        for (int k4 = 0; k4 < 16; ++k4) {
            float4 e = row[k4];
            acc[k4*4+0] += v * e.x;
            acc[k4*4+1] += v * e.y;
            acc[k4*4+2] += v * e.z;
            acc[k4*4+3] += v * e.w;
        }
    }
    float* dst = vp + ((size_t)b * C_DIM + tid) * 64;
#pragma unroll
    for (int k4 = 0; k4 < 16; ++k4)
        reinterpret_cast<float4*>(dst)[k4] =
            make_float4(acc[k4*4+0], acc[k4*4+1], acc[k4*4+2], acc[k4*4+3]);
}

// ---------------------------------------------------------------------------
// attn: per (b,h,n): softmax(q.kp * temp) . vp
// y[b*2097152 + m*32768 + h*8192 + n]  (fp32). grid (32, NH, B), block 256.
// ---------------------------------------------------------------------------
__global__ __launch_bounds__(256) void attn_kernel(
    const float* __restrict__ outq,
    const float* __restrict__ kp,
    const float* __restrict__ vp,
    const float* __restrict__ temp,
    float* __restrict__ y)
{
    __shared__ float kp_lds[64][64];   // [d][k]
    __shared__ float vp_lds[64][64];   // [k][m]
    const int b = blockIdx.z, h = blockIdx.y, t = blockIdx.x;
    const int tid = threadIdx.x;

    const float* kps = kp + ((size_t)b * C_DIM + h * 64) * 64;
    const float* vps = vp + ((size_t)b * C_DIM + h * 64) * 64;
#pragma unroll
    for (int i = 0; i < 16; ++i) {
        int idx = i * 256 + tid;
        kp_lds[idx >> 6][idx & 63] = kps[idx];
        vp_lds[idx >> 6][idx & 63] = vps[idx];
    }
    __syncthreads();

    const int n = t * 256 + tid;
    const float4* q4 = reinterpret_cast<const float4*>(
        outq + ((size_t)b * N_TOK + n) * C_DIM + h * 64);

    float attn[64];
#pragma unroll
    for (int k = 0; k < 64; ++k) attn[k] = 0.f;

    for (int c4 = 0; c4 < 16; ++c4) {
        float4 u = q4[c4];
        float qv[4] = {u.x, u.y, u.z, u.w};
#pragma unroll
        for (int j = 0; j < 4; ++j) {
            const float qd = qv[j];
            const float4* row = reinterpret_cast<const float4*>(kp_lds[c4 * 4 + j]);
#pragma unroll
            for (int k4 = 0; k4 < 16; ++k4) {
                float4 e = row[k4];
                attn[k4*4+0] += qd * e.x;
                attn[k4*4+1] += qd * e.y;
                attn[k4*4+2] += qd * e.z;
                attn[k4*4+3] += qd * e.w;
            }
        }
    }

    const float ts = temp[h];
    float mx = -3.0e38f;
#pragma unroll
    for (int k = 0; k < 64; ++k) { attn[k] *= ts; mx = fmaxf(mx, attn[k]); }
    float sum = 0.f;
#pragma unroll
    for (int k = 0; k < 64; ++k) { float e = __expf(attn[k] - mx); attn[k] = e; sum += e; }
    const float inv = 1.f / sum;
#pragma unroll
    for (int k = 0; k < 64; ++k) attn[k] *= inv;

    float* yb = y + (size_t)b * (N_TOK * C_DIM) + (size_t)h * N_TOK + n;
    const float4* vp4 = reinterpret_cast<const float4*>(&vp_lds[0][0]);
    for (int m4 = 0; m4 < 16; ++m4) {
        float4 r = make_float4(0.f, 0.f, 0.f, 0.f);
#pragma unroll
        for (int k = 0; k < 64; ++k) {
            float4 e = vp4[k * 16 + m4];
            r.x += attn[k] * e.x;
            r.y += attn[k] * e.y;
            r.z += attn[k] * e.z;
            r.w += attn[k] * e.w;
        }
        yb[(size_t)(m4*4+0) * (NH * N_TOK)] = r.x;
        yb[(size_t)(m4*4+1) * (NH * N_TOK)] = r.y;
        yb[(size_t)(m4*4+2) * (NH * N_TOK)] = r.z;
        yb[(size_t)(m4*4+3) * (NH * N_TOK)] = r.w;
    }
}

// ---------------------------------------------------------------------------
// Zero-workspace fallback: block (h, b, tq) recomputes kp/vp in LDS, then
// attention for its quarter of tokens. grid (NH, B, 4), block 256. LDS 64 KB.
// ---------------------------------------------------------------------------
__global__ __launch_bounds__(256) void fused_kernel(
    const float* __restrict__ skip, const float* __restrict__ outq,
    const float* __restrict__ gf,   const float* __restrict__ ef1,
    const float* __restrict__ ef2,  const float* __restrict__ temp,
    float* __restrict__ y)
{
    __shared__ float kp_l[64][64];
    __shared__ float vp_l[64][64];
    __shared__ float stA[64][64];
    __shared__ float stB[64][64];
    const int h = blockIdx.x, b = blockIdx.y, tq = blockIdx.z;
    const int tid = threadIdx.x;
    const int d = tid & 63, q4i = tid >> 6;

    float acc[16];
#pragma unroll
    for (int j = 0; j < 16; ++j) acc[j] = 0.f;

    for (int n0 = 0; n0 < N_TOK; n0 += 64) {
        __syncthreads();
#pragma unroll
        for (int i = 0; i < 16; ++i) {
            int idx = i * 256 + tid; int nn = idx >> 6, dd = idx & 63;
            stA[nn][dd] = skip[((size_t)b * N_TOK + n0 + nn) * C_DIM + h * 64 + dd];
            stB[nn][dd] = ef2[(size_t)(n0 + nn) * 64 + dd];
        }
        __syncthreads();
        for (int nn = 0; nn < 64; ++nn) {
            float v = stA[nn][d];
            const float4* row = reinterpret_cast<const float4*>(&stB[nn][q4i * 16]);
#pragma unroll
            for (int j4 = 0; j4 < 4; ++j4) {
                float4 e = row[j4];
                acc[j4*4+0] += v * e.x; acc[j4*4+1] += v * e.y;
                acc[j4*4+2] += v * e.z; acc[j4*4+3] += v * e.w;
            }
        }
    }
    __syncthreads();
#pragma unroll
    for (int j = 0; j < 16; ++j) kp_l[d][q4i * 16 + j] = acc[j];

#pragma unroll
    for (int j = 0; j < 16; ++j) acc[j] = 0.f;
#pragma unroll
    for (int i = 0; i < 16; ++i) {
        int idx = i * 256 + tid; int nn = idx >> 6, dd = idx & 63;
        stA[nn][dd] = gf[((size_t)b * 64 + nn) * C_DIM + h * 64 + dd];
        stB[nn][dd] = ef1[(size_t)nn * 64 + dd];
    }
    __syncthreads();
    for (int nn = 0; nn < 64; ++nn) {
        float v = stA[nn][d];
        const float4* row = reinterpret_cast<const float4*>(&stB[nn][q4i * 16]);
#pragma unroll
        for (int j4 = 0; j4 < 4; ++j4) {
            float4 e = row[j4];
            acc[j4*4+0] += v * e.x; acc[j4*4+1] += v * e.y;
            acc[j4*4+2] += v * e.z; acc[j4*4+3] += v * e.w;
        }
    }
#pragma unroll
    for (int j = 0; j < 16; ++j) vp_l[d][q4i * 16 + j] = acc[j];
    __syncthreads();

    const float ts = temp[h];
    const float4* vp4 = reinterpret_cast<const float4*>(&vp_l[0][0]);
    for (int t = 0; t < 8; ++t) {
        const int n = tq * 2048 + t * 256 + tid;
        const float4* q4 = reinterpret_cast<const float4*>(
            outq + ((size_t)b * N_TOK + n) * C_DIM + h * 64);
        float attn[64];
#pragma unroll
        for (int k = 0; k < 64; ++k) attn[k] = 0.f;
        for (int c4 = 0; c4 < 16; ++c4) {
            float4 u = q4[c4];
            float qv[4] = {u.x, u.y, u.z, u.w};
#pragma unroll
            for (int j = 0; j < 4; ++j) {
                const float qd = qv[j];
                const float4* row = reinterpret_cast<const float4*>(kp_l[c4 * 4 + j]);
#pragma unroll
                for (int k4 = 0; k4 < 16; ++k4) {
                    float4 e = row[k4];
                    attn[k4*4+0] += qd * e.x;
                    attn[k4*4+1] += qd * e.y;
                    attn[k4*4+2] += qd * e.z;
                    attn[k4*4+3] += qd * e.w;
                }
            }
        }
        float mx = -3.0e38f;
#pragma unroll
        for (int k = 0; k < 64; ++k) { attn[k] *= ts; mx = fmaxf(mx, attn[k]); }
        float sum = 0.f;
#pragma unroll
        for (int k = 0; k < 64; ++k) { float e = __expf(attn[k] - mx); attn[k] = e; sum += e; }
        const float inv = 1.f / sum;
#pragma unroll
        for (int k = 0; k < 64; ++k) attn[k] *= inv;

        float* yb = y + (size_t)b * (N_TOK * C_DIM) + (size_t)h * N_TOK + n;
        for (int m4 = 0; m4 < 16; ++m4) {
            float4 r = make_float4(0.f, 0.f, 0.f, 0.f);
#pragma unroll
            for (int k = 0; k < 64; ++k) {
                float4 e = vp4[k * 16 + m4];
                r.x += attn[k] * e.x;
                r.y += attn[k] * e.y;
                r.z += attn[k] * e.z;
                r.w += attn[k] * e.w;
            }
            yb[(size_t)(m4*4+0) * (NH * N_TOK)] = r.x;
            yb[(size_t)(m4*4+1) * (NH * N_TOK)] = r.y;
            yb[(size_t)(m4*4+2) * (NH * N_TOK)] = r.z;
            yb[(size_t)(m4*4+3) * (NH * N_TOK)] = r.w;
        }
    }
}

extern "C" void kernel_launch(void* const* d_in, const int* in_sizes, int n_in,
                              void* d_out, int out_size, void* d_ws, size_t ws_size,
                              hipStream_t stream) {
    const float* skip = (const float*)d_in[0];
    const float* outq = (const float*)d_in[1];
    const float* gf   = (const float*)d_in[2];
    const float* ef1  = (const float*)d_in[3];
    const float* ef2  = (const float*)d_in[4];
    const float* temp = (const float*)d_in[5];
    float* y = (float*)d_out;

    if (ws_size >= (size_t)524288 * 4) {
        // fast path: exactly 2 MB of ws (kp 1 MB + vp 1 MB)
        float* kp = (float*)d_ws;
        float* vp = kp + 262144;
        zero_kernel<<<256, 256, 0, stream>>>((float4*)d_ws);   // kp only
        kp_atomic_kernel<<<dim3(32, B_SZ), 256, 0, stream>>>(skip, ef2, kp);
        vp_kernel<<<B_SZ, 256, 0, stream>>>(gf, ef1, vp);
        attn_kernel<<<dim3(32, NH, B_SZ), 256, 0, stream>>>(outq, kp, vp, temp, y);
    } else {
        // zero-workspace fallback
        fused_kernel<<<dim3(NH, B_SZ, 4), 256, 0, stream>>>(skip, outq, gf, ef1, ef2, temp, y);
    }
}

// Round 3
// 704.113 us; speedup vs baseline: 3.7966x; 3.7966x over previous
//
#include <hip/hip_runtime.h>
#include <hip/hip_bf16.h>

// GlobalGuideLayer: B=16, N=8192, C=256, h=4, d=64, N1=64, proj=skip_proj=64.
// Dtypes (established rounds 0-4): ALL fp32, inputs AND output, exactly per
// the reference. fp32 logits are precision-critical (logit std ~50, softmax
// near-one-hot: bf16 kp would shift weights ~20%). No fp32 MFMA on CDNA4 ->
// VALU FMA is the compute floor (kp: 27 us, attn: ~55 us).
//
// ATOMIC REGIME LAW (measured r0-r2): device-scope fp32 atomicAdd costs
// exactly 32 B HBM write per lane-op at the round-0/1 pattern (256 blocks,
// 4.19M atomics, 16 consecutive floats per lane, <=16 concurrent blocks per
// kp region). Round 2 (512 blocks, 8.4M atomics, 4x16 pattern) hit a
// contention cliff: 770 B/atomic, 6.3 GB writes, 8x slowdown. NEVER exceed
// the round-1 atomic envelope.
#define B_SZ  16
#define N_TOK 8192
#define C_DIM 256
#define NH    4

// ---------------------------------------------------------------------------
// Zero kp region of ws: 262144 floats = 1 MB (vp is fully overwritten by
// vp_kernel's plain stores - no zeroing needed). grid 256 x 256.
// ---------------------------------------------------------------------------
__global__ __launch_bounds__(256) void zero_kernel(float4* __restrict__ p) {
    p[(size_t)blockIdx.x * 256 + threadIdx.x] = make_float4(0.f, 0.f, 0.f, 0.f);
}

// ---------------------------------------------------------------------------
// kp[b,c,k] = sum_n skip[b,n,c]*EF2[n,k], split-K over 16 chunks of 512
// tokens, atomicAdd partials (fp32 order-noise ~1e-6 << tol).
//
// v4: round-1 grid/atomics (measured benign) + round-2-style ILP compute.
// Thread (cg=tid&63, ks=tid>>6): 4 channels (float4 skip load, lane-
// consecutive -> 1KB/wave-instr) x 4 k's (one wave-uniform ds_read_b128
// broadcast) -> 16-FMA outer product per token. 4-token prefetch pipeline,
// EF2 double-buffered in 2x32KB LDS windows (2 barriers / 2048 FMA).
// Epilogue: LDS transpose ([256][65] pad, one-time ~2us) to round-1's exact
// atomic layout: thread (c=tid&255, kq=tid>>8) does 16 consecutive-float
// atomicAdds -> 4.19M lane-ops, 32B each (measured).
// grid (16, 16), block 1024. LDS 65KB. 1 block/CU, 4 waves/SIMD.
// ---------------------------------------------------------------------------
__global__ __launch_bounds__(1024) void kp_atomic_kernel(
    const float* __restrict__ skip,
    const float* __restrict__ ef2,
    float* __restrict__ kp)
{
    // union: [2][128][64] staging windows (16384 f) / [256][65] transpose (16640 f)
    __shared__ float smraw[16640];
    const int b = blockIdx.y, s = blockIdx.x;
    const int tid = threadIdx.x;
    const int cg = tid & 63;          // channels cg*4..cg*4+3
    const int ks = tid >> 6;          // wave index 0..15 = k-quad ks*4..ks*4+3
    const int n0 = s * 512;

    // ---- stage EF2 window 0, prefetch window 1 ----
    const float4* e4 = reinterpret_cast<const float4*>(ef2 + (size_t)n0 * 64);
    float4* smw4 = reinterpret_cast<float4*>(smraw);
    {
        float4 er0 = e4[tid];
        float4 er1 = e4[1024 + tid];
        smw4[tid] = er0;
        smw4[1024 + tid] = er1;
    }
    float4 en0 = e4[2048 + tid];
    float4 en1 = e4[3072 + tid];
    __syncthreads();

    float acc[16];
#pragma unroll
    for (int k = 0; k < 16; ++k) acc[k] = 0.f;

    // skip[b, n0+g, cg*4..+3] as float4; wave = 64 consecutive float4 = 1KB
    const float4* sp4 = reinterpret_cast<const float4*>(
        skip + ((size_t)b * N_TOK + n0) * C_DIM);

    float4 sc0 = sp4[0 * 64 + cg];
    float4 sc1 = sp4[1 * 64 + cg];
    float4 sc2 = sp4[2 * 64 + cg];
    float4 sc3 = sp4[3 * 64 + cg];

#define OUTER4(sv, ev)                                   \
    acc[ 0] += (sv).x * (ev).x; acc[ 1] += (sv).x * (ev).y; \
    acc[ 2] += (sv).x * (ev).z; acc[ 3] += (sv).x * (ev).w; \
    acc[ 4] += (sv).y * (ev).x; acc[ 5] += (sv).y * (ev).y; \
    acc[ 6] += (sv).y * (ev).z; acc[ 7] += (sv).y * (ev).w; \
    acc[ 8] += (sv).z * (ev).x; acc[ 9] += (sv).z * (ev).y; \
    acc[10] += (sv).z * (ev).z; acc[11] += (sv).z * (ev).w; \
    acc[12] += (sv).w * (ev).x; acc[13] += (sv).w * (ev).y; \
    acc[14] += (sv).w * (ev).z; acc[15] += (sv).w * (ev).w;

    for (int w = 0; w < 4; ++w) {
        const float* buf = smraw + (w & 1) * 8192;       // [128][64] window
        for (int t = 0; t < 128; t += 4) {
            const int g = w * 128 + t;
            const int gp = (g + 4 < 512) ? (g + 4) : 508;  // clamped prefetch
            float4 sn0 = sp4[(gp + 0) * 64 + cg];
            float4 sn1 = sp4[(gp + 1) * 64 + cg];
            float4 sn2 = sp4[(gp + 2) * 64 + cg];
            float4 sn3 = sp4[(gp + 3) * 64 + cg];
            // wave-uniform LDS broadcast reads (ks uniform within wave)
            float4 e0 = *reinterpret_cast<const float4*>(buf + (t + 0) * 64 + ks * 4);
            float4 e1 = *reinterpret_cast<const float4*>(buf + (t + 1) * 64 + ks * 4);
            float4 e2 = *reinterpret_cast<const float4*>(buf + (t + 2) * 64 + ks * 4);
            float4 e3 = *reinterpret_cast<const float4*>(buf + (t + 3) * 64 + ks * 4);
            OUTER4(sc0, e0)
            OUTER4(sc1, e1)
            OUTER4(sc2, e2)
            OUTER4(sc3, e3)
            sc0 = sn0; sc1 = sn1; sc2 = sn2; sc3 = sn3;
        }
        if (w < 3) {
            __syncthreads();   // all waves done reading buf[(w+1)&1] (window w-1)
            float4* d = smw4 + ((w + 1) & 1) * 2048;
            d[tid] = en0;
            d[1024 + tid] = en1;
            if (w < 2) {
                en0 = e4[(w + 2) * 2048 + tid];
                en1 = e4[(w + 2) * 2048 + 1024 + tid];
            }
            __syncthreads();
        }
    }
#undef OUTER4

    // ---- transpose acc through LDS to round-1's exact atomic layout ----
    __syncthreads();                   // done with staging windows
#pragma unroll
    for (int ci = 0; ci < 4; ++ci)
#pragma unroll
        for (int kj = 0; kj < 4; ++kj)
            smraw[(cg * 4 + ci) * 65 + ks * 4 + kj] = acc[ci * 4 + kj];
    __syncthreads();

    const int c  = tid & 255;
    const int kq = tid >> 8;           // 0..3
    float out[16];
#pragma unroll
    for (int j = 0; j < 16; ++j) out[j] = smraw[c * 65 + kq * 16 + j];

    float* dst = kp + ((size_t)b * C_DIM + c) * 64 + kq * 16;
#pragma unroll
    for (int j = 0; j < 16; ++j) atomicAdd(dst + j, out[j]);
}

// ---------------------------------------------------------------------------
// vp[b,c,m] = sum_{n1<64} gf[b,n1,c]*EF1[n1,m]. grid 16, block 256.
// ---------------------------------------------------------------------------
__global__ __launch_bounds__(256) void vp_kernel(
    const float* __restrict__ gf,
    const float* __restrict__ ef1,
    float* __restrict__ vp)
{
    __shared__ float ef1_lds[64][64];      // 16 KB
    const int b = blockIdx.x, tid = threadIdx.x;
    const float4* src = reinterpret_cast<const float4*>(ef1);
    float4* dst_l = reinterpret_cast<float4*>(&ef1_lds[0][0]);
#pragma unroll
    for (int i = 0; i < 4; ++i)            // 1024 float4 = 64 x 64
        dst_l[i * 256 + tid] = src[i * 256 + tid];
    __syncthreads();
    float acc[64];
#pragma unroll
    for (int k = 0; k < 64; ++k) acc[k] = 0.f;
    const float* gp = gf + (size_t)b * 64 * C_DIM + tid;
    for (int n = 0; n < 64; ++n) {
        float v = gp[(size_t)n * C_DIM];
        const float4* row = reinterpret_cast<const float4*>(ef1_lds[n]);
#pragma unroll
        for (int k4 = 0; k4 < 16; ++k4) {
            float4 e = row[k4];
            acc[k4*4+0] += v * e.x;
            acc[k4*4+1] += v * e.y;
            acc[k4*4+2] += v * e.z;
            acc[k4*4+3] += v * e.w;
        }
    }
    float* dst = vp + ((size_t)b * C_DIM + tid) * 64;
#pragma unroll
    for (int k4 = 0; k4 < 16; ++k4)
        reinterpret_cast<float4*>(dst)[k4] =
            make_float4(acc[k4*4+0], acc[k4*4+1], acc[k4*4+2], acc[k4*4+3]);
}

// ---------------------------------------------------------------------------
// attn: per (b,h,n): softmax(q.kp * temp) . vp
// y[b*2097152 + m*32768 + h*8192 + n]  (fp32). grid (32, NH, B), block 256.
// ---------------------------------------------------------------------------
__global__ __launch_bounds__(256) void attn_kernel(
    const float* __restrict__ outq,
    const float* __restrict__ kp,
    const float* __restrict__ vp,
    const float* __restrict__ temp,
    float* __restrict__ y)
{
    __shared__ float kp_lds[64][64];   // [d][k]
    __shared__ float vp_lds[64][64];   // [k][m]
    const int b = blockIdx.z, h = blockIdx.y, t = blockIdx.x;
    const int tid = threadIdx.x;

    const float* kps = kp + ((size_t)b * C_DIM + h * 64) * 64;
    const float* vps = vp + ((size_t)b * C_DIM + h * 64) * 64;
#pragma unroll
    for (int i = 0; i < 16; ++i) {
        int idx = i * 256 + tid;
        kp_lds[idx >> 6][idx & 63] = kps[idx];
        vp_lds[idx >> 6][idx & 63] = vps[idx];
    }
    __syncthreads();

    const int n = t * 256 + tid;
    const float4* q4 = reinterpret_cast<const float4*>(
        outq + ((size_t)b * N_TOK + n) * C_DIM + h * 64);

    float attn[64];
#pragma unroll
    for (int k = 0; k < 64; ++k) attn[k] = 0.f;

    for (int c4 = 0; c4 < 16; ++c4) {
        float4 u = q4[c4];
        float qv[4] = {u.x, u.y, u.z, u.w};
#pragma unroll
        for (int j = 0; j < 4; ++j) {
            const float qd = qv[j];
            const float4* row = reinterpret_cast<const float4*>(kp_lds[c4 * 4 + j]);
#pragma unroll
            for (int k4 = 0; k4 < 16; ++k4) {
                float4 e = row[k4];
                attn[k4*4+0] += qd * e.x;
                attn[k4*4+1] += qd * e.y;
                attn[k4*4+2] += qd * e.z;
                attn[k4*4+3] += qd * e.w;
            }
        }
    }

    const float ts = temp[h];
    float mx = -3.0e38f;
#pragma unroll
    for (int k = 0; k < 64; ++k) { attn[k] *= ts; mx = fmaxf(mx, attn[k]); }
    float sum = 0.f;
#pragma unroll
    for (int k = 0; k < 64; ++k) { float e = __expf(attn[k] - mx); attn[k] = e; sum += e; }
    const float inv = 1.f / sum;
#pragma unroll
    for (int k = 0; k < 64; ++k) attn[k] *= inv;

    float* yb = y + (size_t)b * (N_TOK * C_DIM) + (size_t)h * N_TOK + n;
    const float4* vp4 = reinterpret_cast<const float4*>(&vp_lds[0][0]);
    for (int m4 = 0; m4 < 16; ++m4) {
        float4 r = make_float4(0.f, 0.f, 0.f, 0.f);
#pragma unroll
        for (int k = 0; k < 64; ++k) {
            float4 e = vp4[k * 16 + m4];
            r.x += attn[k] * e.x;
            r.y += attn[k] * e.y;
            r.z += attn[k] * e.z;
            r.w += attn[k] * e.w;
        }
        yb[(size_t)(m4*4+0) * (NH * N_TOK)] = r.x;
        yb[(size_t)(m4*4+1) * (NH * N_TOK)] = r.y;
        yb[(size_t)(m4*4+2) * (NH * N_TOK)] = r.z;
        yb[(size_t)(m4*4+3) * (NH * N_TOK)] = r.w;
    }
}

// ---------------------------------------------------------------------------
// Zero-workspace fallback: block (h, b, tq) recomputes kp/vp in LDS, then
// attention for its quarter of tokens. grid (NH, B, 4), block 256. LDS 64 KB.
// ---------------------------------------------------------------------------
__global__ __launch_bounds__(256) void fused_kernel(
    const float* __restrict__ skip, const float* __restrict__ outq,
    const float* __restrict__ gf,   const float* __restrict__ ef1,
    const float* __restrict__ ef2,  const float* __restrict__ temp,
    float* __restrict__ y)
{
    __shared__ float kp_l[64][64];
    __shared__ float vp_l[64][64];
    __shared__ float stA[64][64];
    __shared__ float stB[64][64];
    const int h = blockIdx.x, b = blockIdx.y, tq = blockIdx.z;
    const int tid = threadIdx.x;
    const int d = tid & 63, q4i = tid >> 6;

    float acc[16];
#pragma unroll
    for (int j = 0; j < 16; ++j) acc[j] = 0.f;

    for (int n0 = 0; n0 < N_TOK; n0 += 64) {
        __syncthreads();
#pragma unroll
        for (int i = 0; i < 16; ++i) {
            int idx = i * 256 + tid; int nn = idx >> 6, dd = idx & 63;
            stA[nn][dd] = skip[((size_t)b * N_TOK + n0 + nn) * C_DIM + h * 64 + dd];
            stB[nn][dd] = ef2[(size_t)(n0 + nn) * 64 + dd];
        }
        __syncthreads();
        for (int nn = 0; nn < 64; ++nn) {
            float v = stA[nn][d];
            const float4* row = reinterpret_cast<const float4*>(&stB[nn][q4i * 16]);
#pragma unroll
            for (int j4 = 0; j4 < 4; ++j4) {
                float4 e = row[j4];
                acc[j4*4+0] += v * e.x; acc[j4*4+1] += v * e.y;
                acc[j4*4+2] += v * e.z; acc[j4*4+3] += v * e.w;
            }
        }
    }
    __syncthreads();
#pragma unroll
    for (int j = 0; j < 16; ++j) kp_l[d][q4i * 16 + j] = acc[j];

#pragma unroll
    for (int j = 0; j < 16; ++j) acc[j] = 0.f;
#pragma unroll
    for (int i = 0; i < 16; ++i) {
        int idx = i * 256 + tid; int nn = idx >> 6, dd = idx & 63;
        stA[nn][dd] = gf[((size_t)b * 64 + nn) * C_DIM + h * 64 + dd];
        stB[nn][dd] = ef1[(size_t)nn * 64 + dd];
    }
    __syncthreads();
    for (int nn = 0; nn < 64; ++nn) {
        float v = stA[nn][d];
        const float4* row = reinterpret_cast<const float4*>(&stB[nn][q4i * 16]);
#pragma unroll
        for (int j4 = 0; j4 < 4; ++j4) {
            float4 e = row[j4];
            acc[j4*4+0] += v * e.x; acc[j4*4+1] += v * e.y;
            acc[j4*4+2] += v * e.z; acc[j4*4+3] += v * e.w;
        }
    }
#pragma unroll
    for (int j = 0; j < 16; ++j) vp_l[d][q4i * 16 + j] = acc[j];
    __syncthreads();

    const float ts = temp[h];
    const float4* vp4 = reinterpret_cast<const float4*>(&vp_l[0][0]);
    for (int t = 0; t < 8; ++t) {
        const int n = tq * 2048 + t * 256 + tid;
        const float4* q4 = reinterpret_cast<const float4*>(
            outq + ((size_t)b * N_TOK + n) * C_DIM + h * 64);
        float attn[64];
#pragma unroll
        for (int k = 0; k < 64; ++k) attn[k] = 0.f;
        for (int c4 = 0; c4 < 16; ++c4) {
            float4 u = q4[c4];
            float qv[4] = {u.x, u.y, u.z, u.w};
#pragma unroll
            for (int j = 0; j < 4; ++j) {
                const float qd = qv[j];
                const float4* row = reinterpret_cast<const float4*>(kp_l[c4 * 4 + j]);
#pragma unroll
                for (int k4 = 0; k4 < 16; ++k4) {
                    float4 e = row[k4];
                    attn[k4*4+0] += qd * e.x;
                    attn[k4*4+1] += qd * e.y;
                    attn[k4*4+2] += qd * e.z;
                    attn[k4*4+3] += qd * e.w;
                }
            }
        }
        float mx = -3.0e38f;
#pragma unroll
        for (int k = 0; k < 64; ++k) { attn[k] *= ts; mx = fmaxf(mx, attn[k]); }
        float sum = 0.f;
#pragma unroll
        for (int k = 0; k < 64; ++k) { float e = __expf(attn[k] - mx); attn[k] = e; sum += e; }
        const float inv = 1.f / sum;
#pragma unroll
        for (int k = 0; k < 64; ++k) attn[k] *= inv;

        float* yb = y + (size_t)b * (N_TOK * C_DIM) + (size_t)h * N_TOK + n;
        for (int m4 = 0; m4 < 16; ++m4) {
            float4 r = make_float4(0.f, 0.f, 0.f, 0.f);
#pragma unroll
            for (int k = 0; k < 64; ++k) {
                float4 e = vp4[k * 16 + m4];
                r.x += attn[k] * e.x;
                r.y += attn[k] * e.y;
                r.z += attn[k] * e.z;
                r.w += attn[k] * e.w;
            }
            yb[(size_t)(m4*4+0) * (NH * N_TOK)] = r.x;
            yb[(size_t)(m4*4+1) * (NH * N_TOK)] = r.y;
            yb[(size_t)(m4*4+2) * (NH * N_TOK)] = r.z;
            yb[(size_t)(m4*4+3) * (NH * N_TOK)] = r.w;
        }
    }
}

extern "C" void kernel_launch(void* const* d_in, const int* in_sizes, int n_in,
                              void* d_out, int out_size, void* d_ws, size_t ws_size,
                              hipStream_t stream) {
    const float* skip = (const float*)d_in[0];
    const float* outq = (const float*)d_in[1];
    const float* gf   = (const float*)d_in[2];
    const float* ef1  = (const float*)d_in[3];
    const float* ef2  = (const float*)d_in[4];
    const float* temp = (const float*)d_in[5];
    float* y = (float*)d_out;

    if (ws_size >= (size_t)524288 * 4) {
        // fast path: exactly 2 MB of ws (kp 1 MB + vp 1 MB)
        float* kp = (float*)d_ws;
        float* vp = kp + 262144;
        zero_kernel<<<256, 256, 0, stream>>>((float4*)d_ws);   // kp only
        kp_atomic_kernel<<<dim3(16, B_SZ), 1024, 0, stream>>>(skip, ef2, kp);
        vp_kernel<<<B_SZ, 256, 0, stream>>>(gf, ef1, vp);
        attn_kernel<<<dim3(32, NH, B_SZ), 256, 0, stream>>>(outq, kp, vp, temp, y);
    } else {
        // zero-workspace fallback
        fused_kernel<<<dim3(NH, B_SZ, 4), 256, 0, stream>>>(skip, outq, gf, ef1, ef2, temp, y);
    }
}

// Round 5
// 499.248 us; speedup vs baseline: 5.3545x; 1.4103x over previous
//
#include <hip/hip_runtime.h>
#include <hip/hip_bf16.h>

// GlobalGuideLayer: B=16, N=8192, C=256, h=4, d=64, N1=64, proj=skip_proj=64.
// Dtypes (established rounds 0-4): ALL fp32, inputs AND output, exactly per
// the reference. fp32 logits are precision-critical (logit std ~50, softmax
// near-one-hot). No fp32 MFMA on CDNA4 -> VALU FMA is the compute floor
// (kp: 27 us, attn: ~14 us VALU / ~41 us HBM).
//
// ATOMIC LESSON (r0-r3): device-scope fp32 atomicAdd write-throughs 32 B/op
// minimum (134 MB for 4.19M ops), and the tail is serialized behind lockstep
// compute -> ~150-200 us floor (r1 and r3: different compute loops, same
// 298 us => limiter was the atomic tail). Round 2's denser pattern hit a
// contention cliff (770 B/op, 6.3 GB). Resolution: NO atomics. Split-K
// partials (16 x 1 MB) go into the dead output buffer y via plain coalesced
// stores; a tiny reduce kernel sums them into kp. y is fully overwritten by
// attn_kernel afterwards (stream-ordered, graph-capture-legal).
//
// r4 bench was an infra failure ("container failed twice", no compile/test
// stage reached). r5 = r4 with kp_partial's launch_bounds relaxed (1024,2):
// VGPR cap 256 instead of 128 (removes any forced-spill / alloc-fail risk;
// residency is 1 block/CU = 16 waves either way).
#define B_SZ  16
#define N_TOK 8192
#define C_DIM 256
#define NH    4

// ---------------------------------------------------------------------------
// kp partials: part[(s*16+b)][c][k] = sum_{n in chunk s} skip[b,n,c]*EF2[n,k]
// grid (16 s, 16 b), block 1024. LDS 64 KB (2x [128][64] EF2 windows).
// Thread (cg=tid&63, ks=tid>>6): 4 channels (float4 skip, lane-consecutive
// -> 1 KB/wave-instr) x 4 k (wave-uniform ds_read_b128 broadcast) -> 16-FMA
// outer product/token. 8-token two-group rotation keeps 8-12 float4 in
// flight (covers ~900 cyc HBM latency). Epilogue: 4 plain float4 stores.
// ---------------------------------------------------------------------------
__global__ __launch_bounds__(1024, 2) void kp_partial_kernel(
    const float* __restrict__ skip,
    const float* __restrict__ ef2,
    float* __restrict__ part)
{
    __shared__ float smraw[2][8192];       // 2 x 32 KB EF2 windows
    const int b = blockIdx.y, s = blockIdx.x;
    const int tid = threadIdx.x;
    const int cg = tid & 63;               // channels cg*4..cg*4+3
    const int ks = tid >> 6;               // wave id = k-quad ks*4..ks*4+3
    const int n0 = s * 512;

    // stage EF2 window 0; prefetch window 1 into regs
    const float4* e4 = reinterpret_cast<const float4*>(ef2 + (size_t)n0 * 64);
    float4* smw4 = reinterpret_cast<float4*>(&smraw[0][0]);
    smw4[tid] = e4[tid];
    smw4[1024 + tid] = e4[1024 + tid];
    float4 en0 = e4[2048 + tid];
    float4 en1 = e4[3072 + tid];
    __syncthreads();

    float acc[16];
#pragma unroll
    for (int k = 0; k < 16; ++k) acc[k] = 0.f;

    const float4* sp4 = reinterpret_cast<const float4*>(
        skip + ((size_t)b * N_TOK + n0) * C_DIM);

#define OUTER4(sv, ev)                                      \
    acc[ 0] += (sv).x * (ev).x; acc[ 1] += (sv).x * (ev).y; \
    acc[ 2] += (sv).x * (ev).z; acc[ 3] += (sv).x * (ev).w; \
    acc[ 4] += (sv).y * (ev).x; acc[ 5] += (sv).y * (ev).y; \
    acc[ 6] += (sv).y * (ev).z; acc[ 7] += (sv).y * (ev).w; \
    acc[ 8] += (sv).z * (ev).x; acc[ 9] += (sv).z * (ev).y; \
    acc[10] += (sv).z * (ev).z; acc[11] += (sv).z * (ev).w; \
    acc[12] += (sv).w * (ev).x; acc[13] += (sv).w * (ev).y; \
    acc[14] += (sv).w * (ev).z; acc[15] += (sv).w * (ev).w;

    // two 4-token register groups, rotated: 8-12 float4 loads in flight
    float4 g0a = sp4[0 * 64 + cg], g0b = sp4[1 * 64 + cg],
           g0c = sp4[2 * 64 + cg], g0d = sp4[3 * 64 + cg];
    float4 g1a = sp4[4 * 64 + cg], g1b = sp4[5 * 64 + cg],
           g1c = sp4[6 * 64 + cg], g1d = sp4[7 * 64 + cg];

    for (int w = 0; w < 4; ++w) {
        const float* buf = smraw[w & 1];
        for (int t = 0; t < 128; t += 8) {
            const int g = w * 128 + t;
            const int p = (g + 8 < 512) ? g + 8 : 504;     // clamped (tail junk unused)
            float4 pa = sp4[(p + 0) * 64 + cg];
            float4 pb = sp4[(p + 1) * 64 + cg];
            float4 pc = sp4[(p + 2) * 64 + cg];
            float4 pd = sp4[(p + 3) * 64 + cg];
            {
                float4 e0 = *reinterpret_cast<const float4*>(buf + (t + 0) * 64 + ks * 4);
                float4 e1 = *reinterpret_cast<const float4*>(buf + (t + 1) * 64 + ks * 4);
                float4 e2 = *reinterpret_cast<const float4*>(buf + (t + 2) * 64 + ks * 4);
                float4 e3 = *reinterpret_cast<const float4*>(buf + (t + 3) * 64 + ks * 4);
                OUTER4(g0a, e0) OUTER4(g0b, e1) OUTER4(g0c, e2) OUTER4(g0d, e3)
            }
            g0a = pa; g0b = pb; g0c = pc; g0d = pd;
            const int q = (g + 12 < 512) ? g + 12 : 504;
            float4 qa = sp4[(q + 0) * 64 + cg];
            float4 qb = sp4[(q + 1) * 64 + cg];
            float4 qc = sp4[(q + 2) * 64 + cg];
            float4 qd = sp4[(q + 3) * 64 + cg];
            {
                float4 e0 = *reinterpret_cast<const float4*>(buf + (t + 4) * 64 + ks * 4);
                float4 e1 = *reinterpret_cast<const float4*>(buf + (t + 5) * 64 + ks * 4);
                float4 e2 = *reinterpret_cast<const float4*>(buf + (t + 6) * 64 + ks * 4);
                float4 e3 = *reinterpret_cast<const float4*>(buf + (t + 7) * 64 + ks * 4);
                OUTER4(g1a, e0) OUTER4(g1b, e1) OUTER4(g1c, e2) OUTER4(g1d, e3)
            }
            g1a = qa; g1b = qb; g1c = qc; g1d = qd;
        }
        if (w < 3) {
            __syncthreads();                       // readers done with other buffer
            float4* d = smw4 + ((w + 1) & 1) * 2048;
            d[tid] = en0;
            d[1024 + tid] = en1;
            if (w < 2) {
                en0 = e4[(w + 2) * 2048 + tid];
                en1 = e4[(w + 2) * 2048 + 1024 + tid];
            }
            __syncthreads();
        }
    }
#undef OUTER4

    // plain stores: part[(s*16+b)][cg*4+ci][ks*4..+4]
    float* dst = part + ((size_t)(s * 16 + b)) * 16384 + (size_t)(cg * 4) * 64 + ks * 4;
#pragma unroll
    for (int ci = 0; ci < 4; ++ci)
        *reinterpret_cast<float4*>(dst + ci * 64) =
            make_float4(acc[ci * 4 + 0], acc[ci * 4 + 1],
                        acc[ci * 4 + 2], acc[ci * 4 + 3]);
}

// ---------------------------------------------------------------------------
// kp[b][c][k] = sum_s part[(s*16+b)][c][k]. grid 256, block 256. ~17 MB traffic.
// ---------------------------------------------------------------------------
__global__ __launch_bounds__(256) void kp_reduce_kernel(
    const float4* __restrict__ part, float4* __restrict__ kp)
{
    const int F = blockIdx.x * 256 + threadIdx.x;   // f4 index, 65536 total
    const int b = F >> 12, r = F & 4095;
    float4 a = make_float4(0.f, 0.f, 0.f, 0.f);
#pragma unroll
    for (int s = 0; s < 16; ++s) {
        float4 p = part[(size_t)(s * 16 + b) * 4096 + r];
        a.x += p.x; a.y += p.y; a.z += p.z; a.w += p.w;
    }
    kp[F] = a;
}

// ---------------------------------------------------------------------------
// vp[b,c,m] = sum_{n1<64} gf[b,n1,c]*EF1[n1,m]. grid 16, block 256.
// ---------------------------------------------------------------------------
__global__ __launch_bounds__(256) void vp_kernel(
    const float* __restrict__ gf,
    const float* __restrict__ ef1,
    float* __restrict__ vp)
{
    __shared__ float ef1_lds[64][64];      // 16 KB
    const int b = blockIdx.x, tid = threadIdx.x;
    const float4* src = reinterpret_cast<const float4*>(ef1);
    float4* dst_l = reinterpret_cast<float4*>(&ef1_lds[0][0]);
#pragma unroll
    for (int i = 0; i < 4; ++i)            // 1024 float4 = 64 x 64
        dst_l[i * 256 + tid] = src[i * 256 + tid];
    __syncthreads();
    float acc[64];
#pragma unroll
    for (int k = 0; k < 64; ++k) acc[k] = 0.f;
    const float* gp = gf + (size_t)b * 64 * C_DIM + tid;
    for (int n = 0; n < 64; ++n) {
        float v = gp[(size_t)n * C_DIM];
        const float4* row = reinterpret_cast<const float4*>(ef1_lds[n]);
#pragma unroll
        for (int k4 = 0; k4 < 16; ++k4) {
            float4 e = row[k4];
            acc[k4*4+0] += v * e.x;
            acc[k4*4+1] += v * e.y;
            acc[k4*4+2] += v * e.z;
            acc[k4*4+3] += v * e.w;
        }
    }
    float* dst = vp + ((size_t)b * C_DIM + tid) * 64;
#pragma unroll
    for (int k4 = 0; k4 < 16; ++k4)
        reinterpret_cast<float4*>(dst)[k4] =
            make_float4(acc[k4*4+0], acc[k4*4+1], acc[k4*4+2], acc[k4*4+3]);
}

// ---------------------------------------------------------------------------
// attn: per (b,h,n): softmax(q.kp * temp) . vp
// y[b*2097152 + m*32768 + h*8192 + n]  (fp32). grid (32, NH, B), block 256.
// v2: __launch_bounds__(256,4) caps VGPR at 128 (~95 live needed) -> 4
// blocks/CU (16 waves) vs 2 before; 1-deep q prefetch. LDS 32 KB.
// ---------------------------------------------------------------------------
__global__ __launch_bounds__(256, 4) void attn_kernel(
    const float* __restrict__ outq,
    const float* __restrict__ kp,
    const float* __restrict__ vp,
    const float* __restrict__ temp,
    float* __restrict__ y)
{
    __shared__ float kp_lds[64][64];   // [d][k]
    __shared__ float vp_lds[64][64];   // [k][m]
    const int b = blockIdx.z, h = blockIdx.y, t = blockIdx.x;
    const int tid = threadIdx.x;

    const float ts = temp[h];
    const float* kps = kp + ((size_t)b * C_DIM + h * 64) * 64;
    const float* vps = vp + ((size_t)b * C_DIM + h * 64) * 64;
#pragma unroll
    for (int i = 0; i < 16; ++i) {
        int idx = i * 256 + tid;
        kp_lds[idx >> 6][idx & 63] = kps[idx];
        vp_lds[idx >> 6][idx & 63] = vps[idx];
    }
    __syncthreads();

    const int n = t * 256 + tid;
    const float4* q4 = reinterpret_cast<const float4*>(
        outq + ((size_t)b * N_TOK + n) * C_DIM + h * 64);

    float attn[64];
#pragma unroll
    for (int k = 0; k < 64; ++k) attn[k] = 0.f;

    float4 u = q4[0];
    for (int c4 = 0; c4 < 16; ++c4) {
        float4 un = (c4 < 15) ? q4[c4 + 1] : u;    // prefetch next q float4
        float qv[4] = {u.x, u.y, u.z, u.w};
#pragma unroll
        for (int j = 0; j < 4; ++j) {
            const float qd = qv[j];
            const float4* row = reinterpret_cast<const float4*>(kp_lds[c4 * 4 + j]);
#pragma unroll
            for (int k4 = 0; k4 < 16; ++k4) {
                float4 e = row[k4];
                attn[k4*4+0] += qd * e.x;
                attn[k4*4+1] += qd * e.y;
                attn[k4*4+2] += qd * e.z;
                attn[k4*4+3] += qd * e.w;
            }
        }
        u = un;
    }

    float mx = -3.0e38f;
#pragma unroll
    for (int k = 0; k < 64; ++k) { attn[k] *= ts; mx = fmaxf(mx, attn[k]); }
    float sum = 0.f;
#pragma unroll
    for (int k = 0; k < 64; ++k) { float e = __expf(attn[k] - mx); attn[k] = e; sum += e; }
    const float inv = 1.f / sum;
#pragma unroll
    for (int k = 0; k < 64; ++k) attn[k] *= inv;

    float* yb = y + (size_t)b * (N_TOK * C_DIM) + (size_t)h * N_TOK + n;
    const float4* vp4 = reinterpret_cast<const float4*>(&vp_lds[0][0]);
    for (int m4 = 0; m4 < 16; ++m4) {
        float4 r = make_float4(0.f, 0.f, 0.f, 0.f);
#pragma unroll
        for (int k = 0; k < 64; ++k) {
            float4 e = vp4[k * 16 + m4];
            r.x += attn[k] * e.x;
            r.y += attn[k] * e.y;
            r.z += attn[k] * e.z;
            r.w += attn[k] * e.w;
        }
        yb[(size_t)(m4*4+0) * (NH * N_TOK)] = r.x;
        yb[(size_t)(m4*4+1) * (NH * N_TOK)] = r.y;
        yb[(size_t)(m4*4+2) * (NH * N_TOK)] = r.z;
        yb[(size_t)(m4*4+3) * (NH * N_TOK)] = r.w;
    }
}

// ---------------------------------------------------------------------------
// Zero-workspace fallback: block (h, b, tq) recomputes kp/vp in LDS, then
// attention for its quarter of tokens. grid (NH, B, 4), block 256. LDS 64 KB.
// ---------------------------------------------------------------------------
__global__ __launch_bounds__(256) void fused_kernel(
    const float* __restrict__ skip, const float* __restrict__ outq,
    const float* __restrict__ gf,   const float* __restrict__ ef1,
    const float* __restrict__ ef2,  const float* __restrict__ temp,
    float* __restrict__ y)
{
    __shared__ float kp_l[64][64];
    __shared__ float vp_l[64][64];
    __shared__ float stA[64][64];
    __shared__ float stB[64][64];
    const int h = blockIdx.x, b = blockIdx.y, tq = blockIdx.z;
    const int tid = threadIdx.x;
    const int d = tid & 63, q4i = tid >> 6;

    float acc[16];
#pragma unroll
    for (int j = 0; j < 16; ++j) acc[j] = 0.f;

    for (int n0 = 0; n0 < N_TOK; n0 += 64) {
        __syncthreads();
#pragma unroll
        for (int i = 0; i < 16; ++i) {
            int idx = i * 256 + tid; int nn = idx >> 6, dd = idx & 63;
            stA[nn][dd] = skip[((size_t)b * N_TOK + n0 + nn) * C_DIM + h * 64 + dd];
            stB[nn][dd] = ef2[(size_t)(n0 + nn) * 64 + dd];
        }
        __syncthreads();
        for (int nn = 0; nn < 64; ++nn) {
            float v = stA[nn][d];
            const float4* row = reinterpret_cast<const float4*>(&stB[nn][q4i * 16]);
#pragma unroll
            for (int j4 = 0; j4 < 4; ++j4) {
                float4 e = row[j4];
                acc[j4*4+0] += v * e.x; acc[j4*4+1] += v * e.y;
                acc[j4*4+2] += v * e.z; acc[j4*4+3] += v * e.w;
            }
        }
    }
    __syncthreads();
#pragma unroll
    for (int j = 0; j < 16; ++j) kp_l[d][q4i * 16 + j] = acc[j];

#pragma unroll
    for (int j = 0; j < 16; ++j) acc[j] = 0.f;
#pragma unroll
    for (int i = 0; i < 16; ++i) {
        int idx = i * 256 + tid; int nn = idx >> 6, dd = idx & 63;
        stA[nn][dd] = gf[((size_t)b * 64 + nn) * C_DIM + h * 64 + dd];
        stB[nn][dd] = ef1[(size_t)nn * 64 + dd];
    }
    __syncthreads();
    for (int nn = 0; nn < 64; ++nn) {
        float v = stA[nn][d];
        const float4* row = reinterpret_cast<const float4*>(&stB[nn][q4i * 16]);
#pragma unroll
        for (int j4 = 0; j4 < 4; ++j4) {
            float4 e = row[j4];
            acc[j4*4+0] += v * e.x; acc[j4*4+1] += v * e.y;
            acc[j4*4+2] += v * e.z; acc[j4*4+3] += v * e.w;
        }
    }
#pragma unroll
    for (int j = 0; j < 16; ++j) vp_l[d][q4i * 16 + j] = acc[j];
    __syncthreads();

    const float ts = temp[h];
    const float4* vp4 = reinterpret_cast<const float4*>(&vp_l[0][0]);
    for (int t = 0; t < 8; ++t) {
        const int n = tq * 2048 + t * 256 + tid;
        const float4* q4 = reinterpret_cast<const float4*>(
            outq + ((size_t)b * N_TOK + n) * C_DIM + h * 64);
        float attn[64];
#pragma unroll
        for (int k = 0; k < 64; ++k) attn[k] = 0.f;
        for (int c4 = 0; c4 < 16; ++c4) {
            float4 u = q4[c4];
            float qv[4] = {u.x, u.y, u.z, u.w};
#pragma unroll
            for (int j = 0; j < 4; ++j) {
                const float qd = qv[j];
                const float4* row = reinterpret_cast<const float4*>(kp_l[c4 * 4 + j]);
#pragma unroll
                for (int k4 = 0; k4 < 16; ++k4) {
                    float4 e = row[k4];
                    attn[k4*4+0] += qd * e.x;
                    attn[k4*4+1] += qd * e.y;
                    attn[k4*4+2] += qd * e.z;
                    attn[k4*4+3] += qd * e.w;
                }
            }
        }
        float mx = -3.0e38f;
#pragma unroll
        for (int k = 0; k < 64; ++k) { attn[k] *= ts; mx = fmaxf(mx, attn[k]); }
        float sum = 0.f;
#pragma unroll
        for (int k = 0; k < 64; ++k) { float e = __expf(attn[k] - mx); attn[k] = e; sum += e; }
        const float inv = 1.f / sum;
#pragma unroll
        for (int k = 0; k < 64; ++k) attn[k] *= inv;

        float* yb = y + (size_t)b * (N_TOK * C_DIM) + (size_t)h * N_TOK + n;
        for (int m4 = 0; m4 < 16; ++m4) {
            float4 r = make_float4(0.f, 0.f, 0.f, 0.f);
#pragma unroll
            for (int k = 0; k < 64; ++k) {
                float4 e = vp4[k * 16 + m4];
                r.x += attn[k] * e.x;
                r.y += attn[k] * e.y;
                r.z += attn[k] * e.z;
                r.w += attn[k] * e.w;
            }
            yb[(size_t)(m4*4+0) * (NH * N_TOK)] = r.x;
            yb[(size_t)(m4*4+1) * (NH * N_TOK)] = r.y;
            yb[(size_t)(m4*4+2) * (NH * N_TOK)] = r.z;
            yb[(size_t)(m4*4+3) * (NH * N_TOK)] = r.w;
        }
    }
}

extern "C" void kernel_launch(void* const* d_in, const int* in_sizes, int n_in,
                              void* d_out, int out_size, void* d_ws, size_t ws_size,
                              hipStream_t stream) {
    const float* skip = (const float*)d_in[0];
    const float* outq = (const float*)d_in[1];
    const float* gf   = (const float*)d_in[2];
    const float* ef1  = (const float*)d_in[3];
    const float* ef2  = (const float*)d_in[4];
    const float* temp = (const float*)d_in[5];
    float* y = (float*)d_out;

    if (ws_size >= (size_t)524288 * 4) {
        // ws: kp 1 MB + vp 1 MB. Split-K partials (16 MB) live in y (dead
        // until attn_kernel fully overwrites it -- stream-ordered, safe).
        float* kp = (float*)d_ws;
        float* vp = kp + 262144;
        float* part = y;
        kp_partial_kernel<<<dim3(16, B_SZ), 1024, 0, stream>>>(skip, ef2, part);
        kp_reduce_kernel<<<256, 256, 0, stream>>>((const float4*)part, (float4*)kp);
        vp_kernel<<<B_SZ, 256, 0, stream>>>(gf, ef1, vp);
        attn_kernel<<<dim3(32, NH, B_SZ), 256, 0, stream>>>(outq, kp, vp, temp, y);
    } else {
        // zero-workspace fallback
        fused_kernel<<<dim3(NH, B_SZ, 4), 256, 0, stream>>>(skip, outq, gf, ef1, ef2, temp, y);
    }
}